// Round 3
// baseline (614.209 us; speedup 1.0000x reference)
//
#include <hip/hip_runtime.h>
#include <hip/hip_bf16.h>
#include <math.h>

// ---------- types ----------
typedef short short8 __attribute__((ext_vector_type(8)));   // 8 bf16 = 4 VGPR MFMA frag
typedef float floatx4 __attribute__((ext_vector_type(4)));  // MFMA accumulator

// ---------- helpers ----------
__device__ __forceinline__ void async16(const void* g, void* l) {
  __builtin_amdgcn_global_load_lds((const __attribute__((address_space(1))) void*)g,
                                   (__attribute__((address_space(3))) void*)l, 16, 0, 0);
}

// ---------- weight cast ----------
__global__ void cvt_kernel(const float* __restrict__ in, __hip_bfloat16* __restrict__ o, int n) {
  int i = blockIdx.x * 256 + threadIdx.x;
  if (i < n) o[i] = __float2bfloat16(in[i]);
}

// ---------- bias+mask table: [cls(4)][head(6)][m(64)][n(64)] fp32 ----------
__global__ void table_kernel(const float* __restrict__ rpb, float* __restrict__ tb) {
  int i = blockIdx.x * 256 + threadIdx.x;
  if (i >= 4 * 6 * 64 * 64) return;
  int n = i & 63, m = (i >> 6) & 63;
  int hc = i >> 12, head = hc % 6, cls = hc / 6;
  float v;
  if (m >= 49 || n >= 49) {
    v = -30000.0f;
  } else {
    int rm = m / 7, cm = m - rm * 7;
    int rn = n / 7, cn = n - rn * 7;
    float bias = rpb[((rm - rn + 6) * 13 + (cm - cn + 6)) * 6 + head];
    int regm = ((cls & 2) ? (rm < 4 ? 1 : 2) : 0) * 3 + ((cls & 1) ? (cm < 4 ? 1 : 2) : 0);
    int regn = ((cls & 2) ? (rn < 4 ? 1 : 2) : 0) * 3 + ((cls & 1) ? (cn < 4 ? 1 : 2) : 0);
    v = bias + (regm != regn ? -100.0f : 0.0f);
  }
  tb[i] = v;
}

// ---------- LayerNorm (optionally fused with roll+window gather), fp32 -> bf16 ----------
template<bool WINDOWED>
__global__ __launch_bounds__(256) void ln_kernel(const float* __restrict__ x,
                                                 const float* __restrict__ g,
                                                 const float* __restrict__ b,
                                                 __hip_bfloat16* __restrict__ out) {
  int w = threadIdx.x >> 6, lane = threadIdx.x & 63;
  int row = blockIdx.x * 4 + w;          // destination row (windowed order if WINDOWED)
  size_t src_row;
  if (WINDOWED) {
    int wi = row / 49, t = row - wi * 49;
    int bb = wi >> 6, wim = wi & 63, wh = wim >> 3, wwn = wim & 7;
    int r = t / 7, c = t - r * 7;
    int y = wh * 7 + r + 3;  if (y >= 56) y -= 56;   // inverse of roll(-3)
    int xp = wwn * 7 + c + 3; if (xp >= 56) xp -= 56;
    src_row = (size_t)bb * 3136 + (size_t)y * 56 + xp;
  } else {
    src_row = row;
  }
  const float* src = x + src_row * 192;
  float v0 = src[lane], v1 = src[lane + 64], v2 = src[lane + 128];
  float s = v0 + v1 + v2;
#pragma unroll
  for (int off = 32; off > 0; off >>= 1) s += __shfl_xor(s, off, 64);
  float mean = s * (1.0f / 192.0f);
  float d0 = v0 - mean, d1 = v1 - mean, d2 = v2 - mean;
  float q = d0 * d0 + d1 * d1 + d2 * d2;
#pragma unroll
  for (int off = 32; off > 0; off >>= 1) q += __shfl_xor(q, off, 64);
  float rstd = rsqrtf(q * (1.0f / 192.0f) + 1e-5f);
  __hip_bfloat16* o = out + (size_t)row * 192;
  o[lane]       = __float2bfloat16(d0 * rstd * g[lane]       + b[lane]);
  o[lane + 64]  = __float2bfloat16(d1 * rstd * g[lane + 64]  + b[lane + 64]);
  o[lane + 128] = __float2bfloat16(d2 * rstd * g[lane + 128] + b[lane + 128]);
}

// ---------- GEMM: C[M,N] = A[M,K] @ B[N,K]^T  (both bf16 row-major, K contiguous) ----------
// BM=256 BN=64 BK=64, 256 threads = 4 waves as row-stripes; each wave computes
// 64x64 via acc[4][4] (m97 ratio: 8 ds_read_b128 -> 32 MFMA per k-chunk pair).
// EPI: 0 = +bias -> bf16 (qkv)
//      1 = +bias + x[dest] -> fp32 at scattered dest (proj + window-reverse + residual)
//      2 = gelu(+bias) -> bf16 (mlp1)
//      3 = +bias + resid[row] -> fp32 in place (mlp2)
template<int K, int EPI>
__global__ __launch_bounds__(256) void gemm_bt(const __hip_bfloat16* __restrict__ A,
                                               const __hip_bfloat16* __restrict__ B,
                                               const float* __restrict__ bias,
                                               const float* residF,
                                               float* outF,
                                               __hip_bfloat16* __restrict__ outB,
                                               int N) {
  __shared__ __hip_bfloat16 sA[256 * 64];   // 32 KB
  __shared__ __hip_bfloat16 sB[64 * 64];    //  8 KB
  const int m0 = blockIdx.y * 256;
  const int n0 = blockIdx.x * 64;
  const int tid = threadIdx.x;
  const int w = tid >> 6, lane = tid & 63;
  const int quad = lane >> 4, l16 = lane & 15;

  floatx4 acc[4][4] = {};

  const __hip_bfloat16* Abase = A + (size_t)m0 * K;
  const __hip_bfloat16* Bbase = B + (size_t)n0 * K;

  for (int k0 = 0; k0 < K; k0 += 64) {
    // stage A tile: 256x64 bf16 = 2048 16B-chunks; chunk c -> row c>>3, k (c&7)*8
    const __hip_bfloat16* Ag = Abase + k0;
#pragma unroll
    for (int it = 0; it < 8; ++it) {
      int c = it * 256 + tid;
      async16(Ag + (size_t)(c >> 3) * K + ((c & 7) << 3), &sA[(c & ~63) * 8]);
    }
    // stage B tile: 64x64 = 512 chunks
    const __hip_bfloat16* Bg = Bbase + k0;
#pragma unroll
    for (int it = 0; it < 2; ++it) {
      int c = it * 256 + tid;
      async16(Bg + (size_t)(c >> 3) * K + ((c & 7) << 3), &sB[(c & ~63) * 8]);
    }
    __syncthreads();   // compiler emits vmcnt(0) drain before barrier

#pragma unroll
    for (int kk = 0; kk < 64; kk += 32) {
      short8 af[4], bf[4];
#pragma unroll
      for (int ri = 0; ri < 4; ++ri)
        af[ri] = *(const short8*)&sA[(w * 64 + ri * 16 + l16) * 64 + kk + quad * 8];
#pragma unroll
      for (int ci = 0; ci < 4; ++ci)
        bf[ci] = *(const short8*)&sB[(ci * 16 + l16) * 64 + kk + quad * 8];
#pragma unroll
      for (int ri = 0; ri < 4; ++ri)
#pragma unroll
        for (int ci = 0; ci < 4; ++ci)
          acc[ri][ci] = __builtin_amdgcn_mfma_f32_16x16x32_bf16(af[ri], bf[ci], acc[ri][ci], 0, 0, 0);
    }
    __syncthreads();
  }

  // epilogue. C/D layout: col = lane&15, row = quad*4 + reg  [m89/m91 verified]
  const int m_base = m0 + w * 64;
#pragma unroll
  for (int ri = 0; ri < 4; ++ri) {
#pragma unroll
    for (int ci = 0; ci < 4; ++ci) {
      const int ccol = n0 + ci * 16 + l16;
      const float bv = bias[ccol];
#pragma unroll
      for (int reg = 0; reg < 4; ++reg) {
        const int row = m_base + ri * 16 + quad * 4 + reg;
        float v = acc[ri][ci][reg] + bv;
        if (EPI == 0) {
          outB[(size_t)row * N + ccol] = __float2bfloat16(v);
        } else if (EPI == 1) {
          int wi = row / 49, t = row - wi * 49;
          int bb = wi >> 6, wim = wi & 63, wh = wim >> 3, wwn = wim & 7;
          int r = t / 7, c = t - r * 7;
          int y = wh * 7 + r + 3;  if (y >= 56) y -= 56;
          int xp = wwn * 7 + c + 3; if (xp >= 56) xp -= 56;
          size_t drow = ((size_t)bb * 3136 + (size_t)y * 56 + xp) * 192 + ccol;
          outF[drow] = v + residF[drow];
        } else if (EPI == 2) {
          float gl = 0.5f * v * (1.0f + erff(v * 0.70710678118654752f));
          outB[(size_t)row * N + ccol] = __float2bfloat16(gl);
        } else {
          size_t o = (size_t)row * 192 + ccol;
          outF[o] = v + residF[o];
        }
      }
    }
  }
}

// ---------- MFMA attention: one wave per (window, head) ----------
__global__ __launch_bounds__(256) void attn_kernel(const __hip_bfloat16* __restrict__ qkv,
                                                   const float* __restrict__ table,
                                                   __hip_bfloat16* __restrict__ out) {
  __shared__ __hip_bfloat16 Plds[4][64 * 72];
  __shared__ __hip_bfloat16 Vt[4][32 * 64];
  const int slot = threadIdx.x >> 6, lane = threadIdx.x & 63;
  const int quad = lane >> 4, l16 = lane & 15;

  const int wg = blockIdx.x * 4 + slot;      // 0..12287
  const int wi = wg / 6, head = wg - wi * 6;
  const int wim = wi & 63, wh = wim >> 3, wwn = wim & 7;
  const int cls = ((wh == 7) ? 2 : 0) + ((wwn == 7) ? 1 : 0);
  const __hip_bfloat16* base = qkv + (size_t)wi * 49 * 576 + head * 32;

  // ---- stage V transposed into LDS: Vt[n][k] = V[k][n], k>=49 zeroed ----
  const __hip_bfloat16* vbase = base + 384;
#pragma unroll
  for (int it = 0; it < 4; ++it) {
    int p = it * 64 + lane;                 // 196 chunks of 8 bf16 (49 rows x 4)
    if (p < 196) {
      int k = p >> 2, c = p & 3;
      short8 sv = *(const short8*)(vbase + k * 576 + c * 8);
#pragma unroll
      for (int j = 0; j < 8; ++j)
        Vt[slot][(c * 8 + j) * 64 + k] = ((const __hip_bfloat16*)&sv)[j];
    }
  }
#pragma unroll
  for (int it = 0; it < 8; ++it) {          // zero pad k in [49,64)
    int p = it * 64 + lane;
    if (p < 480) {
      int k = 49 + (p >> 5), n = p & 31;
      Vt[slot][n * 64 + k] = __float2bfloat16(0.0f);
    }
  }

  // ---- load Q/K fragments straight from global (A/B layout: row l16+16t, k=quad*8) ----
  short8 aq[4], bk[4];
#pragma unroll
  for (int t = 0; t < 4; ++t) {
    int m = l16 + 16 * t; if (m > 48) m = 48;   // clamp pad rows (killed by table/softmax)
    aq[t] = *(const short8*)(base + m * 576 + quad * 8);
    bk[t] = *(const short8*)(base + 192 + m * 576 + quad * 8);
  }

  // ---- S = Q@K^T ----
  floatx4 sc[4][4] = {};
#pragma unroll
  for (int ti = 0; ti < 4; ++ti)
#pragma unroll
    for (int tj = 0; tj < 4; ++tj)
      sc[ti][tj] = __builtin_amdgcn_mfma_f32_16x16x32_bf16(aq[ti], bk[tj], sc[ti][tj], 0, 0, 0);

  // ---- softmax (rows across quad's 16 lanes) + write P to LDS ----
  const float scale = 0.17677669529663689f;  // 1/sqrt(32)
  const float* tb = table + (((size_t)cls * 6 + head) << 12);
  float linv[4][4];
#pragma unroll
  for (int ti = 0; ti < 4; ++ti) {
#pragma unroll
    for (int r = 0; r < 4; ++r) {
      const int row = 16 * ti + quad * 4 + r;
      const float* trow = tb + row * 64 + l16;
      float v0 = sc[ti][0][r] * scale + trow[0];
      float v1 = sc[ti][1][r] * scale + trow[16];
      float v2 = sc[ti][2][r] * scale + trow[32];
      float v3 = sc[ti][3][r] * scale + trow[48];
      float mx = fmaxf(fmaxf(v0, v1), fmaxf(v2, v3));
      mx = fmaxf(mx, __shfl_xor(mx, 1));
      mx = fmaxf(mx, __shfl_xor(mx, 2));
      mx = fmaxf(mx, __shfl_xor(mx, 4));
      mx = fmaxf(mx, __shfl_xor(mx, 8));
      v0 = __expf(v0 - mx); v1 = __expf(v1 - mx);
      v2 = __expf(v2 - mx); v3 = __expf(v3 - mx);
      float sm = (v0 + v1) + (v2 + v3);
      sm += __shfl_xor(sm, 1);
      sm += __shfl_xor(sm, 2);
      sm += __shfl_xor(sm, 4);
      sm += __shfl_xor(sm, 8);
      linv[ti][r] = 1.0f / sm;
      __hip_bfloat16* pr = &Plds[slot][row * 72 + l16];
      pr[0]  = __float2bfloat16(v0);
      pr[16] = __float2bfloat16(v1);
      pr[32] = __float2bfloat16(v2);
      pr[48] = __float2bfloat16(v3);
    }
  }
  __syncthreads();   // order LDS writes (Vt + P) before PV reads

  // ---- O = P@V ----
  floatx4 oc[4][2] = {};
#pragma unroll
  for (int kb = 0; kb < 64; kb += 32) {
    short8 ap[4], bv[2];
#pragma unroll
    for (int ti = 0; ti < 4; ++ti)
      ap[ti] = *(const short8*)&Plds[slot][(l16 + 16 * ti) * 72 + kb + quad * 8];
#pragma unroll
    for (int t2 = 0; t2 < 2; ++t2)
      bv[t2] = *(const short8*)&Vt[slot][(l16 + 16 * t2) * 64 + kb + quad * 8];
#pragma unroll
    for (int ti = 0; ti < 4; ++ti)
#pragma unroll
      for (int t2 = 0; t2 < 2; ++t2)
        oc[ti][t2] = __builtin_amdgcn_mfma_f32_16x16x32_bf16(ap[ti], bv[t2], oc[ti][t2], 0, 0, 0);
  }

  // ---- epilogue: row = 16ti+quad*4+reg (<49), col = l16+16t2 ----
#pragma unroll
  for (int ti = 0; ti < 4; ++ti) {
#pragma unroll
    for (int reg = 0; reg < 4; ++reg) {
      const int row = 16 * ti + quad * 4 + reg;
      if (row < 49) {
        __hip_bfloat16* op = out + ((size_t)wi * 49 + row) * 192 + head * 32 + l16;
        const float li = linv[ti][reg];
        op[0]  = __float2bfloat16(oc[ti][0][reg] * li);
        op[16] = __float2bfloat16(oc[ti][1][reg] * li);
      }
    }
  }
}

// ---------- launch ----------
extern "C" void kernel_launch(void* const* d_in, const int* in_sizes, int n_in,
                              void* d_out, int out_size, void* d_ws, size_t ws_size,
                              hipStream_t stream) {
  const float* x      = (const float*)d_in[0];
  const float* qkv_w  = (const float*)d_in[1];
  const float* qkv_b  = (const float*)d_in[2];
  const float* proj_w = (const float*)d_in[3];
  const float* proj_b = (const float*)d_in[4];
  const float* rpb    = (const float*)d_in[5];
  const float* n1g    = (const float*)d_in[6];
  const float* n1b    = (const float*)d_in[7];
  const float* n2g    = (const float*)d_in[8];
  const float* n2b    = (const float*)d_in[9];
  const float* w1     = (const float*)d_in[10];
  const float* b1     = (const float*)d_in[11];
  const float* w2     = (const float*)d_in[12];
  const float* b2     = (const float*)d_in[13];
  float* out = (float*)d_out;

  char* ws = (char*)d_ws;
  // region B: qkv (100352x576 bf16 = 115.6MB) then reused as h_mlp (100352x768 bf16 = 154.1MB)
  __hip_bfloat16* bufB = (__hip_bfloat16*)ws;
  // region A: win_ln1 / attn_out / ln2 (100352x192 bf16 = 38.5MB)
  __hip_bfloat16* bufA = (__hip_bfloat16*)(ws + 154140672);
  // bf16 weights
  __hip_bfloat16* wqb = (__hip_bfloat16*)(ws + 154140672 + 38535168);
  __hip_bfloat16* wpb = wqb + 110592;
  __hip_bfloat16* w1b = wpb + 36864;
  __hip_bfloat16* w2b = w1b + 147456;
  // bias+mask table: 4*6*64*64 fp32 = 384KB
  float* tablef = (float*)(ws + 154140672 + 38535168 + 884736);

  cvt_kernel<<<(110592 + 255) / 256, 256, 0, stream>>>(qkv_w, wqb, 110592);
  cvt_kernel<<<(36864  + 255) / 256, 256, 0, stream>>>(proj_w, wpb, 36864);
  cvt_kernel<<<(147456 + 255) / 256, 256, 0, stream>>>(w1, w1b, 147456);
  cvt_kernel<<<(147456 + 255) / 256, 256, 0, stream>>>(w2, w2b, 147456);
  table_kernel<<<384, 256, 0, stream>>>(rpb, tablef);

  // LN1 + shift + window partition -> bufA (windowed rows, bf16)
  ln_kernel<true><<<25088, 256, 0, stream>>>(x, n1g, n1b, bufA);
  // qkv = bufA @ qkv_w^T + b -> bufB (100352 x 576 bf16)
  gemm_bt<192, 0><<<dim3(9, 392), 256, 0, stream>>>(bufA, wqb, qkv_b, nullptr, nullptr, bufB, 576);
  // attention -> bufA (windowed rows, bf16, 100352 x 192)
  attn_kernel<<<3072, 256, 0, stream>>>(bufB, tablef, bufA);
  // proj + window-reverse + residual -> d_out (x2, fp32)
  gemm_bt<192, 1><<<dim3(3, 392), 256, 0, stream>>>(bufA, wpb, proj_b, x, out, nullptr, 192);
  // LN2 -> bufA (bf16, image row order)
  ln_kernel<false><<<25088, 256, 0, stream>>>(out, n2g, n2b, bufA);
  // MLP1 + gelu -> bufB (100352 x 768 bf16)
  gemm_bt<192, 2><<<dim3(12, 392), 256, 0, stream>>>(bufA, w1b, b1, nullptr, nullptr, bufB, 768);
  // MLP2 + residual, in place on d_out
  gemm_bt<768, 3><<<dim3(3, 392), 256, 0, stream>>>(bufB, w2b, b2, out, out, nullptr, 192);
}

// Round 4
// 522.800 us; speedup vs baseline: 1.1748x; 1.1748x over previous
//
#include <hip/hip_runtime.h>
#include <hip/hip_bf16.h>
#include <math.h>

// ---------- types ----------
typedef short short8 __attribute__((ext_vector_type(8)));   // 8 bf16 = 4 VGPR MFMA frag
typedef float floatx4 __attribute__((ext_vector_type(4)));  // MFMA accumulator

// ---------- helpers ----------
__device__ __forceinline__ void async16(const void* g, void* l) {
  __builtin_amdgcn_global_load_lds((const __attribute__((address_space(1))) void*)g,
                                   (__attribute__((address_space(3))) void*)l, 16, 0, 0);
}

// ---------- weight cast ----------
__global__ void cvt_kernel(const float* __restrict__ in, __hip_bfloat16* __restrict__ o, int n) {
  int i = blockIdx.x * 256 + threadIdx.x;
  if (i < n) o[i] = __float2bfloat16(in[i]);
}

// ---------- bias+mask table: [cls(4)][head(6)][m(64)][n(64)] fp32 ----------
__global__ void table_kernel(const float* __restrict__ rpb, float* __restrict__ tb) {
  int i = blockIdx.x * 256 + threadIdx.x;
  if (i >= 4 * 6 * 64 * 64) return;
  int n = i & 63, m = (i >> 6) & 63;
  int hc = i >> 12, head = hc % 6, cls = hc / 6;
  float v;
  if (m >= 49 || n >= 49) {
    v = -30000.0f;
  } else {
    int rm = m / 7, cm = m - rm * 7;
    int rn = n / 7, cn = n - rn * 7;
    float bias = rpb[((rm - rn + 6) * 13 + (cm - cn + 6)) * 6 + head];
    int regm = ((cls & 2) ? (rm < 4 ? 1 : 2) : 0) * 3 + ((cls & 1) ? (cm < 4 ? 1 : 2) : 0);
    int regn = ((cls & 2) ? (rn < 4 ? 1 : 2) : 0) * 3 + ((cls & 1) ? (cn < 4 ? 1 : 2) : 0);
    v = bias + (regm != regn ? -100.0f : 0.0f);
  }
  tb[i] = v;
}

// ---------- LayerNorm (optionally fused with roll+window gather), fp32 -> bf16 ----------
template<bool WINDOWED>
__global__ __launch_bounds__(256) void ln_kernel(const float* __restrict__ x,
                                                 const float* __restrict__ g,
                                                 const float* __restrict__ b,
                                                 __hip_bfloat16* __restrict__ out) {
  int w = threadIdx.x >> 6, lane = threadIdx.x & 63;
  int row = blockIdx.x * 4 + w;          // destination row (windowed order if WINDOWED)
  size_t src_row;
  if (WINDOWED) {
    int wi = row / 49, t = row - wi * 49;
    int bb = wi >> 6, wim = wi & 63, wh = wim >> 3, wwn = wim & 7;
    int r = t / 7, c = t - r * 7;
    int y = wh * 7 + r + 3;  if (y >= 56) y -= 56;   // inverse of roll(-3)
    int xp = wwn * 7 + c + 3; if (xp >= 56) xp -= 56;
    src_row = (size_t)bb * 3136 + (size_t)y * 56 + xp;
  } else {
    src_row = row;
  }
  const float* src = x + src_row * 192;
  float v0 = src[lane], v1 = src[lane + 64], v2 = src[lane + 128];
  float s = v0 + v1 + v2;
#pragma unroll
  for (int off = 32; off > 0; off >>= 1) s += __shfl_xor(s, off, 64);
  float mean = s * (1.0f / 192.0f);
  float d0 = v0 - mean, d1 = v1 - mean, d2 = v2 - mean;
  float q = d0 * d0 + d1 * d1 + d2 * d2;
#pragma unroll
  for (int off = 32; off > 0; off >>= 1) q += __shfl_xor(q, off, 64);
  float rstd = rsqrtf(q * (1.0f / 192.0f) + 1e-5f);
  __hip_bfloat16* o = out + (size_t)row * 192;
  o[lane]       = __float2bfloat16(d0 * rstd * g[lane]       + b[lane]);
  o[lane + 64]  = __float2bfloat16(d1 * rstd * g[lane + 64]  + b[lane + 64]);
  o[lane + 128] = __float2bfloat16(d2 * rstd * g[lane + 128] + b[lane + 128]);
}

// ---------- GEMM (R2-proven): BM=128 BN=64 BK=64, 4 waves 2x2, acc[4][2] ----------
// EPI: 0 = +bias -> bf16 (qkv)
//      1 = +bias + x[dest] -> fp32 at scattered dest (proj + window-reverse + residual)
template<int K, int EPI>
__global__ __launch_bounds__(256) void gemm_bt(const __hip_bfloat16* __restrict__ A,
                                               const __hip_bfloat16* __restrict__ B,
                                               const float* __restrict__ bias,
                                               const float* residF,
                                               float* outF,
                                               __hip_bfloat16* __restrict__ outB,
                                               int N) {
  __shared__ __hip_bfloat16 sA[128 * 64];
  __shared__ __hip_bfloat16 sB[64 * 64];
  const int m0 = blockIdx.y * 128;
  const int n0 = blockIdx.x * 64;
  const int tid = threadIdx.x;
  const int w = tid >> 6, lane = tid & 63;
  const int quad = lane >> 4, l16 = lane & 15;
  const int wr = w >> 1, wc = w & 1;   // wave tile: rows [wr*64,+64), cols [wc*32,+32)

  floatx4 acc[4][2] = {};

  const __hip_bfloat16* Abase = A + (size_t)m0 * K;
  const __hip_bfloat16* Bbase = B + (size_t)n0 * K;

  for (int k0 = 0; k0 < K; k0 += 64) {
    const __hip_bfloat16* Ag = Abase + k0;
#pragma unroll
    for (int it = 0; it < 4; ++it) {
      int cb = ((it * 4 + w) << 6);
      int c = cb + lane;
      async16(Ag + (size_t)(c >> 3) * K + ((c & 7) << 3), &sA[cb * 8]);
    }
    const __hip_bfloat16* Bg = Bbase + k0;
#pragma unroll
    for (int it = 0; it < 2; ++it) {
      int cb = ((it * 4 + w) << 6);
      int c = cb + lane;
      async16(Bg + (size_t)(c >> 3) * K + ((c & 7) << 3), &sB[cb * 8]);
    }
    __syncthreads();

#pragma unroll
    for (int kk = 0; kk < 64; kk += 32) {
      short8 af[4], bf[2];
#pragma unroll
      for (int ri = 0; ri < 4; ++ri)
        af[ri] = *(const short8*)&sA[(wr * 64 + ri * 16 + l16) * 64 + kk + quad * 8];
#pragma unroll
      for (int ci = 0; ci < 2; ++ci)
        bf[ci] = *(const short8*)&sB[(wc * 32 + ci * 16 + l16) * 64 + kk + quad * 8];
#pragma unroll
      for (int ri = 0; ri < 4; ++ri)
#pragma unroll
        for (int ci = 0; ci < 2; ++ci)
          acc[ri][ci] = __builtin_amdgcn_mfma_f32_16x16x32_bf16(af[ri], bf[ci], acc[ri][ci], 0, 0, 0);
    }
    __syncthreads();
  }

  // epilogue. C/D layout: col = lane&15, row = quad*4 + reg  [m89/m91 verified]
  const int m_base = m0 + wr * 64;
#pragma unroll
  for (int ri = 0; ri < 4; ++ri) {
#pragma unroll
    for (int ci = 0; ci < 2; ++ci) {
      const int ccol = n0 + wc * 32 + ci * 16 + l16;
      const float bv = bias[ccol];
#pragma unroll
      for (int reg = 0; reg < 4; ++reg) {
        const int row = m_base + ri * 16 + quad * 4 + reg;
        float v = acc[ri][ci][reg] + bv;
        if (EPI == 0) {
          outB[(size_t)row * N + ccol] = __float2bfloat16(v);
        } else {
          int wi = row / 49, t = row - wi * 49;
          int bb = wi >> 6, wim = wi & 63, wh = wim >> 3, wwn = wim & 7;
          int r = t / 7, c = t - r * 7;
          int y = wh * 7 + r + 3;  if (y >= 56) y -= 56;
          int xp = wwn * 7 + c + 3; if (xp >= 56) xp -= 56;
          size_t drow = ((size_t)bb * 3136 + (size_t)y * 56 + xp) * 192 + ccol;
          outF[drow] = v + residF[drow];
        }
      }
    }
  }
}

// ---------- fused MLP: out += gelu(ln2 @ W1^T + b1) @ W2^T + b2 ----------
// Block = 64 rows. A-row frags persistent in regs (K=192 = full row).
// Loop hb over 24 hidden-chunks of 32: stage W1c(12KB)+W2c(12KB) via async16,
// phase1 MFMA -> gelu -> bf16 H in LDS -> phase2 MFMA into acc[2][6] (fp32 64x192).
// Occupancy-first: LDS 29.7KB, launch_bounds(256,3) -> 3 blocks/CU.
__global__ __launch_bounds__(256, 3) void mlp_kernel(const __hip_bfloat16* __restrict__ A,
                                                     const __hip_bfloat16* __restrict__ W1,
                                                     const float* __restrict__ b1,
                                                     const __hip_bfloat16* __restrict__ W2,
                                                     const float* __restrict__ b2,
                                                     float* __restrict__ out) {
  __shared__ __hip_bfloat16 sW1[32 * 192];   // 12 KB, row-major (hidden, k) packed
  __shared__ __hip_bfloat16 sW2[192 * 32];   // 12 KB, row-major (outcol, kk) packed
  __shared__ __hip_bfloat16 sH[64 * 40];     // 5 KB, stride 40 (pad)
  const int tid = threadIdx.x;
  const int w = tid >> 6, lane = tid & 63;
  const int quad = lane >> 4, l16 = lane & 15;
  const int wr = w >> 1, wc = w & 1;
  const size_t rowblk = (size_t)blockIdx.x * 64;

  // persistent A fragments: phase-1 rows = w*16 + l16, k = quad*8 + 32j
  short8 af[6];
  {
    const __hip_bfloat16* arow = A + (rowblk + w * 16 + l16) * 192 + quad * 8;
#pragma unroll
    for (int j = 0; j < 6; ++j) af[j] = *(const short8*)(arow + 32 * j);
  }

  floatx4 acc[2][6] = {};   // out tile: rows wr*32 + mi*16, cols wc*96 + ni*16

  for (int hb = 0; hb < 768; hb += 32) {
    __syncthreads();   // protect sW1/sW2/sH from still-reading waves of prev iter
    {
      // W1 chunk: 32 consecutive rows x 192 k = contiguous 12288 B
      const char* s1 = (const char*)(W1 + hb * 192);
#pragma unroll
      for (int it = 0; it < 3; ++it) {
        int c = it * 256 + tid;
        async16(s1 + c * 16, (char*)sW1 + c * 16);
      }
      // W2 chunk: 192 rows, 64 B each (row stride 1536 B)
      const char* s2 = (const char*)W2 + hb * 2;
#pragma unroll
      for (int it = 0; it < 3; ++it) {
        int c = it * 256 + tid;
        async16(s2 + (size_t)(c >> 2) * 1536 + (c & 3) * 16, (char*)sW2 + c * 16);
      }
    }
    __syncthreads();   // drain async16 (vmcnt0 before barrier)

    // ---- phase 1: hc[16x32] = A[w-rows] @ W1c^T ----
    floatx4 hc[2] = {};
#pragma unroll
    for (int j = 0; j < 6; ++j) {
#pragma unroll
      for (int t = 0; t < 2; ++t) {
        short8 bw = *(const short8*)&sW1[(t * 16 + l16) * 192 + j * 32 + quad * 8];
        hc[t] = __builtin_amdgcn_mfma_f32_16x16x32_bf16(af[j], bw, hc[t], 0, 0, 0);
      }
    }
    // gelu(+b1) -> sH  (C layout: row = w*16 + quad*4 + r, col = t*16 + l16)
#pragma unroll
    for (int t = 0; t < 2; ++t) {
      const float bv = b1[hb + t * 16 + l16];
#pragma unroll
      for (int r = 0; r < 4; ++r) {
        float v = hc[t][r] + bv;
        float g = 0.5f * v * (1.0f + erff(v * 0.70710678118654752f));
        sH[(w * 16 + quad * 4 + r) * 40 + t * 16 + l16] = __float2bfloat16(g);
      }
    }
    __syncthreads();   // H visible to all waves

    // ---- phase 2: acc += H[rows wr*32..] @ W2c^T[cols wc*96..] ----
    short8 ah[2], bw2[6];
#pragma unroll
    for (int mi = 0; mi < 2; ++mi)
      ah[mi] = *(const short8*)&sH[(wr * 32 + mi * 16 + l16) * 40 + quad * 8];
#pragma unroll
    for (int ni = 0; ni < 6; ++ni)
      bw2[ni] = *(const short8*)&sW2[(wc * 96 + ni * 16 + l16) * 32 + quad * 8];
#pragma unroll
    for (int mi = 0; mi < 2; ++mi)
#pragma unroll
      for (int ni = 0; ni < 6; ++ni)
        acc[mi][ni] = __builtin_amdgcn_mfma_f32_16x16x32_bf16(ah[mi], bw2[ni], acc[mi][ni], 0, 0, 0);
  }

  // ---- epilogue: out[row][col] = resid + acc + b2  (in place) ----
#pragma unroll
  for (int mi = 0; mi < 2; ++mi) {
#pragma unroll
    for (int ni = 0; ni < 6; ++ni) {
      const int ccol = wc * 96 + ni * 16 + l16;
      const float bv = b2[ccol];
#pragma unroll
      for (int r = 0; r < 4; ++r) {
        const size_t row = rowblk + wr * 32 + mi * 16 + quad * 4 + r;
        float* p = out + row * 192 + ccol;
        *p = *p + acc[mi][ni][r] + bv;
      }
    }
  }
}

// ---------- MFMA attention: one wave per (window, head) ----------
__global__ __launch_bounds__(256) void attn_kernel(const __hip_bfloat16* __restrict__ qkv,
                                                   const float* __restrict__ table,
                                                   __hip_bfloat16* __restrict__ out) {
  __shared__ __hip_bfloat16 Plds[4][64 * 72];
  __shared__ __hip_bfloat16 Vt[4][32 * 64];
  const int slot = threadIdx.x >> 6, lane = threadIdx.x & 63;
  const int quad = lane >> 4, l16 = lane & 15;

  const int wg = blockIdx.x * 4 + slot;      // 0..12287
  const int wi = wg / 6, head = wg - wi * 6;
  const int wim = wi & 63, wh = wim >> 3, wwn = wim & 7;
  const int cls = ((wh == 7) ? 2 : 0) + ((wwn == 7) ? 1 : 0);
  const __hip_bfloat16* base = qkv + (size_t)wi * 49 * 576 + head * 32;

  // ---- stage V transposed into LDS: Vt[n][k] = V[k][n], k>=49 zeroed ----
  const __hip_bfloat16* vbase = base + 384;
#pragma unroll
  for (int it = 0; it < 4; ++it) {
    int p = it * 64 + lane;                 // 196 chunks of 8 bf16 (49 rows x 4)
    if (p < 196) {
      int k = p >> 2, c = p & 3;
      short8 sv = *(const short8*)(vbase + k * 576 + c * 8);
#pragma unroll
      for (int j = 0; j < 8; ++j)
        Vt[slot][(c * 8 + j) * 64 + k] = ((const __hip_bfloat16*)&sv)[j];
    }
  }
#pragma unroll
  for (int it = 0; it < 8; ++it) {          // zero pad k in [49,64)
    int p = it * 64 + lane;
    if (p < 480) {
      int k = 49 + (p >> 5), n = p & 31;
      Vt[slot][n * 64 + k] = __float2bfloat16(0.0f);
    }
  }

  // ---- load Q/K fragments straight from global (A/B layout: row l16+16t, k=quad*8) ----
  short8 aq[4], bk[4];
#pragma unroll
  for (int t = 0; t < 4; ++t) {
    int m = l16 + 16 * t; if (m > 48) m = 48;   // clamp pad rows (killed by table/softmax)
    aq[t] = *(const short8*)(base + m * 576 + quad * 8);
    bk[t] = *(const short8*)(base + 192 + m * 576 + quad * 8);
  }

  // ---- S = Q@K^T ----
  floatx4 sc[4][4] = {};
#pragma unroll
  for (int ti = 0; ti < 4; ++ti)
#pragma unroll
    for (int tj = 0; tj < 4; ++tj)
      sc[ti][tj] = __builtin_amdgcn_mfma_f32_16x16x32_bf16(aq[ti], bk[tj], sc[ti][tj], 0, 0, 0);

  // ---- softmax (rows across quad's 16 lanes) + write P to LDS ----
  const float scale = 0.17677669529663689f;  // 1/sqrt(32)
  const float* tb = table + (((size_t)cls * 6 + head) << 12);
  float linv[4][4];
#pragma unroll
  for (int ti = 0; ti < 4; ++ti) {
#pragma unroll
    for (int r = 0; r < 4; ++r) {
      const int row = 16 * ti + quad * 4 + r;
      const float* trow = tb + row * 64 + l16;
      float v0 = sc[ti][0][r] * scale + trow[0];
      float v1 = sc[ti][1][r] * scale + trow[16];
      float v2 = sc[ti][2][r] * scale + trow[32];
      float v3 = sc[ti][3][r] * scale + trow[48];
      float mx = fmaxf(fmaxf(v0, v1), fmaxf(v2, v3));
      mx = fmaxf(mx, __shfl_xor(mx, 1));
      mx = fmaxf(mx, __shfl_xor(mx, 2));
      mx = fmaxf(mx, __shfl_xor(mx, 4));
      mx = fmaxf(mx, __shfl_xor(mx, 8));
      v0 = __expf(v0 - mx); v1 = __expf(v1 - mx);
      v2 = __expf(v2 - mx); v3 = __expf(v3 - mx);
      float sm = (v0 + v1) + (v2 + v3);
      sm += __shfl_xor(sm, 1);
      sm += __shfl_xor(sm, 2);
      sm += __shfl_xor(sm, 4);
      sm += __shfl_xor(sm, 8);
      linv[ti][r] = 1.0f / sm;
      __hip_bfloat16* pr = &Plds[slot][row * 72 + l16];
      pr[0]  = __float2bfloat16(v0);
      pr[16] = __float2bfloat16(v1);
      pr[32] = __float2bfloat16(v2);
      pr[48] = __float2bfloat16(v3);
    }
  }
  __syncthreads();   // order LDS writes (Vt + P) before PV reads

  // ---- O = P@V ----
  floatx4 oc[4][2] = {};
#pragma unroll
  for (int kb = 0; kb < 64; kb += 32) {
    short8 ap[4], bv[2];
#pragma unroll
    for (int ti = 0; ti < 4; ++ti)
      ap[ti] = *(const short8*)&Plds[slot][(l16 + 16 * ti) * 72 + kb + quad * 8];
#pragma unroll
    for (int t2 = 0; t2 < 2; ++t2)
      bv[t2] = *(const short8*)&Vt[slot][(l16 + 16 * t2) * 64 + kb + quad * 8];
#pragma unroll
    for (int ti = 0; ti < 4; ++ti)
#pragma unroll
      for (int t2 = 0; t2 < 2; ++t2)
        oc[ti][t2] = __builtin_amdgcn_mfma_f32_16x16x32_bf16(ap[ti], bv[t2], oc[ti][t2], 0, 0, 0);
  }

  // ---- epilogue: row = 16ti+quad*4+reg (<49), col = l16+16t2 ----
#pragma unroll
  for (int ti = 0; ti < 4; ++ti) {
#pragma unroll
    for (int reg = 0; reg < 4; ++reg) {
      const int row = 16 * ti + quad * 4 + reg;
      if (row < 49) {
        __hip_bfloat16* op = out + ((size_t)wi * 49 + row) * 192 + head * 32 + l16;
        const float li = linv[ti][reg];
        op[0]  = __float2bfloat16(oc[ti][0][reg] * li);
        op[16] = __float2bfloat16(oc[ti][1][reg] * li);
      }
    }
  }
}

// ---------- launch ----------
extern "C" void kernel_launch(void* const* d_in, const int* in_sizes, int n_in,
                              void* d_out, int out_size, void* d_ws, size_t ws_size,
                              hipStream_t stream) {
  const float* x      = (const float*)d_in[0];
  const float* qkv_w  = (const float*)d_in[1];
  const float* qkv_b  = (const float*)d_in[2];
  const float* proj_w = (const float*)d_in[3];
  const float* proj_b = (const float*)d_in[4];
  const float* rpb    = (const float*)d_in[5];
  const float* n1g    = (const float*)d_in[6];
  const float* n1b    = (const float*)d_in[7];
  const float* n2g    = (const float*)d_in[8];
  const float* n2b    = (const float*)d_in[9];
  const float* w1     = (const float*)d_in[10];
  const float* b1     = (const float*)d_in[11];
  const float* w2     = (const float*)d_in[12];
  const float* b2     = (const float*)d_in[13];
  float* out = (float*)d_out;

  char* ws = (char*)d_ws;
  // region B: qkv (100352x576 bf16 = 115.6MB)
  __hip_bfloat16* bufB = (__hip_bfloat16*)ws;
  // region A: win_ln1 / attn_out / ln2 (100352x192 bf16 = 38.5MB)
  __hip_bfloat16* bufA = (__hip_bfloat16*)(ws + 115605504);
  // bf16 weights
  __hip_bfloat16* wqb = (__hip_bfloat16*)(ws + 115605504 + 38535168);
  __hip_bfloat16* wpb = wqb + 110592;
  __hip_bfloat16* w1b = wpb + 36864;
  __hip_bfloat16* w2b = w1b + 147456;
  // bias+mask table: 4*6*64*64 fp32 = 384KB
  float* tablef = (float*)(ws + 115605504 + 38535168 + 884736);

  cvt_kernel<<<(110592 + 255) / 256, 256, 0, stream>>>(qkv_w, wqb, 110592);
  cvt_kernel<<<(36864  + 255) / 256, 256, 0, stream>>>(proj_w, wpb, 36864);
  cvt_kernel<<<(147456 + 255) / 256, 256, 0, stream>>>(w1, w1b, 147456);
  cvt_kernel<<<(147456 + 255) / 256, 256, 0, stream>>>(w2, w2b, 147456);
  table_kernel<<<384, 256, 0, stream>>>(rpb, tablef);

  // LN1 + shift + window partition -> bufA (windowed rows, bf16)
  ln_kernel<true><<<25088, 256, 0, stream>>>(x, n1g, n1b, bufA);
  // qkv = bufA @ qkv_w^T + b -> bufB (100352 x 576 bf16)
  gemm_bt<192, 0><<<dim3(9, 784), 256, 0, stream>>>(bufA, wqb, qkv_b, nullptr, nullptr, bufB, 576);
  // attention -> bufA (windowed rows, bf16, 100352 x 192)
  attn_kernel<<<3072, 256, 0, stream>>>(bufB, tablef, bufA);
  // proj + window-reverse + residual -> d_out (x2, fp32)
  gemm_bt<192, 1><<<dim3(3, 784), 256, 0, stream>>>(bufA, wpb, proj_b, x, out, nullptr, 192);
  // LN2 -> bufA (bf16, image row order)
  ln_kernel<false><<<25088, 256, 0, stream>>>(out, n2g, n2b, bufA);
  // fused MLP: out += gelu(bufA @ W1^T + b1) @ W2^T + b2
  mlp_kernel<<<1568, 256, 0, stream>>>(bufA, w1b, b1, w2b, b2, out);
}